// Round 8
// baseline (669.485 us; speedup 1.0000x reference)
//
#include <hip/hip_runtime.h>

// Side Window Filter — bit-exact vs harness np ref (absmax 0.0 contract).
// Math contract (DO NOT REORDER): per output, each of the 8 windows is a
// sequential fma chain over its taps in row-major (i,j) order, fp32
// accumulator starting at 0, weights fp32(1/15), fp32(1/9); replicate
// boundary; 8 iterations; fp32 iterates; fp32 d/argmin(first-idx)/update;
// final clip(|x0-res|,0,255).
//
// R18 = R15 pair-row structure + three counter-driven fixes:
//  1. amdgpu_waves_per_eu(4,4): register budget EXACTLY 128 (4 waves/EU),
//     and no incentive for the allocator to shrink below it (R17's
//     min-only form let it pick 64 regs and re-cluster loads; R16's
//     max=3 capped runtime occupancy). 4/EU = 50% occupancy cap, above
//     the ~25% we ever reach, so the cap cannot bind.
//  2. Packed fp32 math: column pairs (0,1) and (2,3) run their 8 window
//     chains as float2 via __builtin_elementwise_fma -> v_pk_fma_f32.
//     Both halves are independent fp32 IEEE fmas; each accumulator chain
//     keeps its exact sequential tap order -> bit-exact. Halves the fma
//     instruction count (768 -> 384 per thread).
//  3. XCD-contiguous y-banding (proven in R17: FETCH 103 -> 55.7 MB).
//
// Pair dataflow: each thread owns 4 columns x output rows (2y, 2y+1);
// walk the 6-row window union once; union row i feeds phase i of row A
// (i<=4) and phase i-1 of row B (i>=1) from the same 5 float4 loads.

static constexpr int H      = 2048;
static constexpr int W      = 2048;
static constexpr int C      = 3;
static constexpr int WC     = W * C;       // 6144 floats per row
static constexpr int NBX    = 6;           // x-blocks (256 thr x 4 cols)
static constexpr int NPAIRS = H / 2;       // 1024 row-pairs
static constexpr int BAND   = NPAIRS / 8;  // 128 y-pairs per XCD band

typedef float v2f __attribute__((ext_vector_type(2)));

__device__ __forceinline__ v2f pkfma(v2f a, v2f b, v2f c) {
  return __builtin_elementwise_fma(a, b, c);
}

// One window-row phase of the 8 directional chains for one COLUMN PAIR.
// kp in {0,1} selects columns (2kp, 2kp+1); ph compile-time at every call
// site. Chain statement order identical to the verified R10/R15 kernels;
// the two vector halves are the two columns' independent chains.
__device__ __forceinline__ void apply_phase_pk(v2f* __restrict__ a,
                                               const float* __restrict__ r,
                                               int kp, int ph, v2f& center,
                                               v2f w15, v2f w9) {
  const int b = 2 * kp;
  const v2f t0 = {r[b+2],  r[b+3]};
  const v2f t1 = {r[b+5],  r[b+6]};
  const v2f t2 = {r[b+8],  r[b+9]};
  const v2f t3 = {r[b+11], r[b+12]};
  const v2f t4 = {r[b+14], r[b+15]};
  if (ph == 2) center = t2;
  // L: cols 0..2, all rows
  a[0]=pkfma(w15,t0,a[0]); a[0]=pkfma(w15,t1,a[0]); a[0]=pkfma(w15,t2,a[0]);
  // R: cols 2..4, all rows
  a[1]=pkfma(w15,t2,a[1]); a[1]=pkfma(w15,t3,a[1]); a[1]=pkfma(w15,t4,a[1]);
  if (ph <= 2) {  // U: rows 0..2, all cols
    a[2]=pkfma(w15,t0,a[2]); a[2]=pkfma(w15,t1,a[2]); a[2]=pkfma(w15,t2,a[2]);
    a[2]=pkfma(w15,t3,a[2]); a[2]=pkfma(w15,t4,a[2]);
    // NW / NE
    a[4]=pkfma(w9,t0,a[4]); a[4]=pkfma(w9,t1,a[4]); a[4]=pkfma(w9,t2,a[4]);
    a[5]=pkfma(w9,t2,a[5]); a[5]=pkfma(w9,t3,a[5]); a[5]=pkfma(w9,t4,a[5]);
  }
  if (ph >= 2) {  // D: rows 2..4, all cols
    a[3]=pkfma(w15,t0,a[3]); a[3]=pkfma(w15,t1,a[3]); a[3]=pkfma(w15,t2,a[3]);
    a[3]=pkfma(w15,t3,a[3]); a[3]=pkfma(w15,t4,a[3]);
    // SW / SE
    a[6]=pkfma(w9,t0,a[6]); a[6]=pkfma(w9,t1,a[6]); a[6]=pkfma(w9,t2,a[6]);
    a[7]=pkfma(w9,t2,a[7]); a[7]=pkfma(w9,t3,a[7]); a[7]=pkfma(w9,t4,a[7]);
  }
}

// fp32 d/argmin/update epilogue for one column = one vector half.
// h is a compile-time literal at every call site.
__device__ __forceinline__ float finish_half(const v2f* __restrict__ a,
                                             float center, int h) {
  float best  = a[0][h] - center;
  float besta = fabsf(best);
#pragma unroll
  for (int m = 1; m < 8; ++m) {
    const float d  = a[m][h] - center;
    const float ab = fabsf(d);
    if (ab < besta) { besta = ab; best = d; }
  }
  return center + best;
}

// epilogue + float4 store for one output row (acc = 2 col-pairs x 8)
template<bool FINAL>
__device__ __forceinline__ void emit_row(const v2f acc[2][8],
                                         const v2f* __restrict__ center,
                                         int y, int col4,
                                         const float* __restrict__ x0,
                                         float* __restrict__ dst) {
  float4 xv4;
  if (FINAL) xv4 = *(const float4*)(x0 + (size_t)y * WC + col4);
  float o[4];
#pragma unroll
  for (int kp = 0; kp < 2; ++kp)
#pragma unroll
    for (int h = 0; h < 2; ++h) {
      const int k = 2 * kp + h;
      const float res = finish_half(acc[kp], center[kp][h], h);
      if (FINAL) {
        const float xv = (k == 0) ? xv4.x : (k == 1) ? xv4.y
                       : (k == 2) ? xv4.z : xv4.w;
        float diff = fabsf(xv - res);
        o[k] = diff > 255.0f ? 255.0f : diff;
      } else {
        o[k] = res;
      }
    }
  float4 ov;
  ov.x = o[0]; ov.y = o[1]; ov.z = o[2]; ov.w = o[3];
  *(float4*)(dst + (size_t)y * WC + col4) = ov;
}

template<bool FINAL>
__global__
__attribute__((amdgpu_flat_work_group_size(256, 256), amdgpu_waves_per_eu(4, 4)))
void swf_pk(const float* __restrict__ src, float* __restrict__ dst,
            const float* __restrict__ x0) {
  // XCD-contiguous y-banding (R17-proven): flat%8 ~ XCD id -> 128-pair band
  const int flat  = blockIdx.y * NBX + blockIdx.x;
  const int xcd   = flat & 7;
  const int idx   = flat >> 3;
  const int yb    = idx / NBX;
  const int xb    = idx - yb * NBX;
  const int ypair = xcd * BAND + yb;
  const int col4  = (xb * 256 + threadIdx.x) * 4;   // 16B-aligned
  const int yA    = ypair * 2;                      // rows yA, yA+1

  const v2f w15 = {1.0f / 15.0f, 1.0f / 15.0f};
  const v2f w9  = {1.0f / 9.0f,  1.0f / 9.0f};

  v2f accA[2][8], accB[2][8];
#pragma unroll
  for (int kp = 0; kp < 2; ++kp)
#pragma unroll
    for (int m = 0; m < 8; ++m) {
      accA[kp][m] = (v2f){0.0f, 0.0f};
      accB[kp][m] = (v2f){0.0f, 0.0f};
    }
  v2f centerA[2], centerB[2];

  // fast iff all taps for cols col4..col4+3 lie in [col4-8, col4+12)
  const bool fastc = (col4 >= 8) && (col4 <= WC - 12);
  if (fastc) {
    const float* colbase = src + (col4 - 8);
    // union rows i=0..5: phase i of A (i<=4), phase i-1 of B (i>=1)
#pragma unroll
    for (int i = 0; i < 6; ++i) {
      int hy = yA + i - 2;
      hy = hy < 0 ? 0 : (hy > H - 1 ? H - 1 : hy);     // replicate rows
      const float4* rp = (const float4*)(colbase + (size_t)hy * WC);
      const float4 q0 = rp[0], q1 = rp[1], q2 = rp[2], q3 = rp[3], q4 = rp[4];
      const float r[20] = {q0.x,q0.y,q0.z,q0.w, q1.x,q1.y,q1.z,q1.w,
                           q2.x,q2.y,q2.z,q2.w, q3.x,q3.y,q3.z,q3.w,
                           q4.x,q4.y,q4.z,q4.w};
#pragma unroll
      for (int kp = 0; kp < 2; ++kp) {
        if (i <= 4) apply_phase_pk(accA[kp], r, kp, i,     centerA[kp], w15, w9);
        if (i >= 1) apply_phase_pk(accB[kp], r, kp, i - 1, centerB[kp], w15, w9);
      }
    }
  } else {
    // edge columns (col4 in {0,4,WC-8,WC-4}): build the same 20-float
    // window per row via pixel-clamped scalar loads (halo identity:
    // float x <-> unclamped idx f = col4-8+x; channel preserved).
    const int base = col4 - 8;
#pragma unroll
    for (int i = 0; i < 6; ++i) {
      int hy = yA + i - 2;
      hy = hy < 0 ? 0 : (hy > H - 1 ? H - 1 : hy);
      const float* rr = src + (size_t)hy * WC;
      float r[20];
#pragma unroll
      for (int x = 0; x < 20; ++x) {
        const int f = base + x;
        const int ix = (f < 0)    ? ((f % 3) + 3) % 3
                     : (f >= WC)  ? (W - 1) * 3 + (f % 3)
                     : f;
        r[x] = rr[ix];
      }
#pragma unroll
      for (int kp = 0; kp < 2; ++kp) {
        if (i <= 4) apply_phase_pk(accA[kp], r, kp, i,     centerA[kp], w15, w9);
        if (i >= 1) apply_phase_pk(accB[kp], r, kp, i - 1, centerB[kp], w15, w9);
      }
    }
  }

  // epilogue: two output rows, fp32 d/argmin/update, float4 stores
  emit_row<FINAL>(accA, centerA, yA,     col4, x0, dst);
  emit_row<FINAL>(accB, centerB, yA + 1, col4, x0, dst);
}

extern "C" void kernel_launch(void* const* d_in, const int* in_sizes, int n_in,
                              void* d_out, int out_size, void* d_ws, size_t ws_size,
                              hipStream_t stream) {
  const float* x0  = (const float*)d_in[0];
  float*       out = (float*)d_out;
  float*       ws  = (float*)d_ws;   // needs H*W*C*4 = 50.3 MB

  dim3 grid(NBX, NPAIRS);            // 6 x-blocks, 1024 row-pairs
  dim3 block(256);

  swf_pk<false><<<grid, block, 0, stream>>>(x0,  ws,  nullptr);  // iter 1
  swf_pk<false><<<grid, block, 0, stream>>>(ws,  out, nullptr);  // iter 2
  swf_pk<false><<<grid, block, 0, stream>>>(out, ws,  nullptr);  // iter 3
  swf_pk<false><<<grid, block, 0, stream>>>(ws,  out, nullptr);  // iter 4
  swf_pk<false><<<grid, block, 0, stream>>>(out, ws,  nullptr);  // iter 5
  swf_pk<false><<<grid, block, 0, stream>>>(ws,  out, nullptr);  // iter 6
  swf_pk<false><<<grid, block, 0, stream>>>(out, ws,  nullptr);  // iter 7
  swf_pk<true ><<<grid, block, 0, stream>>>(ws,  out, x0);       // iter 8 + diff
}

// Round 9
// 454.331 us; speedup vs baseline: 1.4736x; 1.4736x over previous
//
#include <hip/hip_runtime.h>

// Side Window Filter — bit-exact vs harness np ref (absmax 0.0 contract).
// Math contract (DO NOT REORDER): per output, each of the 8 windows is a
// sequential __builtin_fmaf chain over its taps in row-major (i,j) order,
// fp32 accumulator starting at 0, weights fp32(1/15), fp32(1/9); replicate
// boundary; 8 iterations; fp32 iterates; fp32 d/argmin(first-idx)/update;
// final clip(|x0-res|,0,255).
//
// R19 = R15 EXACTLY (pair-processing, flat global float4 loads, no LDS,
// amdgpu_waves_per_eu(3,3)+launch_bounds(256) -> VGPR 84, best measured:
// 57.3 us/dispatch, 458.8 us total) + the single R17-PROVEN fix:
// XCD-contiguous y-banding (FETCH 103->55.7 MB in R17). Block IDs are
// remapped so flat%8 (the XCD round-robin residue) selects a contiguous
// 128-row-pair band; adjacent y-pairs share 4/6 input rows and now reuse
// the same XCD's L2 instead of re-fetching from HBM. Nothing else
// changed — same attributes, same body, same schedule.
//
// Allocator lesson (R14/R16/R17/R18, n=4): this toolchain caps this
// kernel at ~84-92 VGPRs regardless of launch_bounds/waves_per_eu
// variants; structures must fit that budget. R15's ~4-float spill
// (~25 MB/dispatch scratch traffic) is the accepted cost of pair rows.

static constexpr int H      = 2048;
static constexpr int W      = 2048;
static constexpr int C      = 3;
static constexpr int WC     = W * C;       // 6144 floats per row
static constexpr int NBX    = 6;           // x-blocks (256 thr x 4 cols)
static constexpr int NPAIRS = H / 2;       // 1024 row-pairs
static constexpr int BAND   = NPAIRS / 8;  // 128 y-pairs per XCD band

// One window-row phase of the 8 directional chains for one output column.
// ph is compile-time at every call site (unrolled loops) so branches fold.
// Chain statement order is IDENTICAL to the verified R10/R15 kernels.
__device__ __forceinline__ void apply_phase_t(float* __restrict__ a,
                                              float t0, float t1, float t2,
                                              float t3, float t4,
                                              int ph, float& center,
                                              float w15, float w9) {
  if (ph == 2) center = t2;
  // L: cols 0..2, all rows
  a[0]=__builtin_fmaf(w15,t0,a[0]); a[0]=__builtin_fmaf(w15,t1,a[0]); a[0]=__builtin_fmaf(w15,t2,a[0]);
  // R: cols 2..4, all rows
  a[1]=__builtin_fmaf(w15,t2,a[1]); a[1]=__builtin_fmaf(w15,t3,a[1]); a[1]=__builtin_fmaf(w15,t4,a[1]);
  if (ph <= 2) {  // U: rows 0..2, all cols
    a[2]=__builtin_fmaf(w15,t0,a[2]); a[2]=__builtin_fmaf(w15,t1,a[2]); a[2]=__builtin_fmaf(w15,t2,a[2]);
    a[2]=__builtin_fmaf(w15,t3,a[2]); a[2]=__builtin_fmaf(w15,t4,a[2]);
    // NW / NE
    a[4]=__builtin_fmaf(w9,t0,a[4]); a[4]=__builtin_fmaf(w9,t1,a[4]); a[4]=__builtin_fmaf(w9,t2,a[4]);
    a[5]=__builtin_fmaf(w9,t2,a[5]); a[5]=__builtin_fmaf(w9,t3,a[5]); a[5]=__builtin_fmaf(w9,t4,a[5]);
  }
  if (ph >= 2) {  // D: rows 2..4, all cols
    a[3]=__builtin_fmaf(w15,t0,a[3]); a[3]=__builtin_fmaf(w15,t1,a[3]); a[3]=__builtin_fmaf(w15,t2,a[3]);
    a[3]=__builtin_fmaf(w15,t3,a[3]); a[3]=__builtin_fmaf(w15,t4,a[3]);
    // SW / SE
    a[6]=__builtin_fmaf(w9,t0,a[6]); a[6]=__builtin_fmaf(w9,t1,a[6]); a[6]=__builtin_fmaf(w9,t2,a[6]);
    a[7]=__builtin_fmaf(w9,t2,a[7]); a[7]=__builtin_fmaf(w9,t3,a[7]); a[7]=__builtin_fmaf(w9,t4,a[7]);
  }
}

// fp32 d/argmin/update epilogue for one output column (order-contractual).
__device__ __forceinline__ float finish(const float* __restrict__ a,
                                        float center) {
  float best  = a[0] - center;
  float besta = fabsf(best);
#pragma unroll
  for (int m = 1; m < 8; ++m) {
    const float d  = a[m] - center;
    const float ab = fabsf(d);
    if (ab < besta) { besta = ab; best = d; }
  }
  return center + best;
}

template<bool FINAL>
__global__ __attribute__((amdgpu_waves_per_eu(3, 3))) __launch_bounds__(256)
void swf_pg(const float* __restrict__ src, float* __restrict__ dst,
            const float* __restrict__ x0) {
  // R17-proven XCD-contiguous y-banding: flat%8 ~ XCD id -> contiguous
  // 128-pair band; everything downstream identical to R15.
  const int flat  = blockIdx.y * NBX + blockIdx.x;
  const int xcd   = flat & 7;
  const int idx   = flat >> 3;
  const int yb    = idx / NBX;
  const int xb    = idx - yb * NBX;
  const int ypair = xcd * BAND + yb;
  const int col4  = (xb * 256 + threadIdx.x) * 4;   // 16B-aligned
  const int yA    = ypair * 2;                      // rows yA, yA+1

  const float w15 = 1.0f / 15.0f;   // fp32(1/15)
  const float w9  = 1.0f / 9.0f;    // fp32(1/9)

  float accA[4][8], accB[4][8];
#pragma unroll
  for (int k = 0; k < 4; ++k)
#pragma unroll
    for (int m = 0; m < 8; ++m) { accA[k][m] = 0.0f; accB[k][m] = 0.0f; }
  float centerA[4], centerB[4];

  // fast iff all taps for cols col4..col4+3 lie in [col4-8, col4+12)
  const bool fastc = (col4 >= 8) && (col4 <= WC - 12);
  if (fastc) {
    const float* colbase = src + (col4 - 8);
    // walk the 6-row union: row yA+i-2 feeds phase i of A (i<=4) and
    // phase i-1 of B (i>=1)
#pragma unroll
    for (int i = 0; i < 6; ++i) {
      int hy = yA + i - 2;
      hy = hy < 0 ? 0 : (hy > H - 1 ? H - 1 : hy);     // replicate rows
      const float4* rp = (const float4*)(colbase + (size_t)hy * WC);
      const float4 q0 = rp[0], q1 = rp[1], q2 = rp[2], q3 = rp[3], q4 = rp[4];
      const float r[20] = {q0.x,q0.y,q0.z,q0.w, q1.x,q1.y,q1.z,q1.w,
                           q2.x,q2.y,q2.z,q2.w, q3.x,q3.y,q3.z,q3.w,
                           q4.x,q4.y,q4.z,q4.w};
#pragma unroll
      for (int k = 0; k < 4; ++k) {
        // tap j of output col4+k -> r[k + 3j + 2]
        const float t0 = r[k+2], t1 = r[k+5], t2 = r[k+8],
                    t3 = r[k+11], t4 = r[k+14];
        if (i <= 4) apply_phase_t(accA[k], t0,t1,t2,t3,t4, i,     centerA[k], w15, w9);
        if (i >= 1) apply_phase_t(accB[k], t0,t1,t2,t3,t4, i - 1, centerB[k], w15, w9);
      }
    }
  } else {
    // edge columns (col4 in {0,4,WC-8,WC-4}): scalar clamped gather,
    // identical chain structure; column clamps hoisted (row-invariant)
    int cjk[4][5];
#pragma unroll
    for (int k = 0; k < 4; ++k) {
      const int col = col4 + k;
      const int w   = col / 3;
      const int c   = col - w * 3;
#pragma unroll
      for (int j = 0; j < 5; ++j) {
        int wj = w + j - 2;
        wj = wj < 0 ? 0 : (wj > W - 1 ? W - 1 : wj);   // replicate cols
        cjk[k][j] = wj * 3 + c;
      }
    }
#pragma unroll
    for (int i = 0; i < 6; ++i) {
      int hy = yA + i - 2;
      hy = hy < 0 ? 0 : (hy > H - 1 ? H - 1 : hy);
      const float* rr = src + (size_t)hy * WC;
#pragma unroll
      for (int k = 0; k < 4; ++k) {
        const float t0 = rr[cjk[k][0]], t1 = rr[cjk[k][1]], t2 = rr[cjk[k][2]],
                    t3 = rr[cjk[k][3]], t4 = rr[cjk[k][4]];
        if (i <= 4) apply_phase_t(accA[k], t0,t1,t2,t3,t4, i,     centerA[k], w15, w9);
        if (i >= 1) apply_phase_t(accB[k], t0,t1,t2,t3,t4, i - 1, centerB[k], w15, w9);
      }
    }
  }

  // epilogue: two output rows, fp32 d/argmin/update, float4 stores
#pragma unroll
  for (int half = 0; half < 2; ++half) {
    const int y = yA + half;
    float4 xv4;
    if (FINAL) xv4 = *(const float4*)(x0 + (size_t)y * WC + col4);
    float o[4];
#pragma unroll
    for (int k = 0; k < 4; ++k) {
      const float res = half ? finish(accB[k], centerB[k])
                             : finish(accA[k], centerA[k]);
      if (FINAL) {
        const float xv = (k == 0) ? xv4.x : (k == 1) ? xv4.y
                       : (k == 2) ? xv4.z : xv4.w;
        float diff = fabsf(xv - res);
        o[k] = diff > 255.0f ? 255.0f : diff;
      } else {
        o[k] = res;
      }
    }
    float4 ov;
    ov.x = o[0]; ov.y = o[1]; ov.z = o[2]; ov.w = o[3];
    *(float4*)(dst + (size_t)y * WC + col4) = ov;
  }
}

extern "C" void kernel_launch(void* const* d_in, const int* in_sizes, int n_in,
                              void* d_out, int out_size, void* d_ws, size_t ws_size,
                              hipStream_t stream) {
  const float* x0  = (const float*)d_in[0];
  float*       out = (float*)d_out;
  float*       ws  = (float*)d_ws;   // needs H*W*C*4 = 50.3 MB

  dim3 grid(NBX, NPAIRS);            // 6 x-blocks, 1024 row-pairs
  dim3 block(256);

  swf_pg<false><<<grid, block, 0, stream>>>(x0,  ws,  nullptr);  // iter 1
  swf_pg<false><<<grid, block, 0, stream>>>(ws,  out, nullptr);  // iter 2
  swf_pg<false><<<grid, block, 0, stream>>>(out, ws,  nullptr);  // iter 3
  swf_pg<false><<<grid, block, 0, stream>>>(ws,  out, nullptr);  // iter 4
  swf_pg<false><<<grid, block, 0, stream>>>(out, ws,  nullptr);  // iter 5
  swf_pg<false><<<grid, block, 0, stream>>>(ws,  out, nullptr);  // iter 6
  swf_pg<false><<<grid, block, 0, stream>>>(out, ws,  nullptr);  // iter 7
  swf_pg<true ><<<grid, block, 0, stream>>>(ws,  out, x0);       // iter 8 + diff
}